// Round 14
// baseline (823.497 us; speedup 1.0000x reference)
//
#include <hip/hip_runtime.h>
#include <math.h>

#define NN 50000
#define NF 512
#define NH 512
#define NK 16
#define NSLICE 8            // 512 dims / 8 = 64 dims (64 B fp8) per slice, slice-major

typedef __attribute__((ext_vector_type(8))) short bf16x8;
typedef __attribute__((ext_vector_type(4))) float f32x4;
typedef __attribute__((ext_vector_type(2))) float f32x2;

typedef __attribute__((address_space(3))) void lds_v;
typedef const __attribute__((address_space(1))) void gbl_v;

#define RPART 128   // reduce_cs_nl blocks
#define TPART 2048  // trace blocks (grid-stride, 2 edges/thread)

__device__ __forceinline__ unsigned short f2bf(float f) {
  unsigned u = __float_as_uint(f);
  unsigned r = (u + 0x7fffu + ((u >> 16) & 1u)) >> 16;
  return (unsigned short)r;
}

__device__ __forceinline__ float selu_f(float v) {
  const float SC = 1.0507009873554805f, AL = 1.6732632423543772f;
  return (v > 0.f) ? SC * v : SC * AL * (expf(v) - 1.f);
}

// ---------------- fp32 -> bf16 feature conversion (once) ----------------
__global__ __launch_bounds__(256) void conv_feat(const float* __restrict__ X,
                                                 unsigned short* __restrict__ Xb, int n4) {
  for (int i = blockIdx.x * blockDim.x + threadIdx.x; i < n4; i += gridDim.x * blockDim.x) {
    float4 v = *(const float4*)(X + (size_t)i * 4);
    ushort4 o;
    o.x = f2bf(v.x); o.y = f2bf(v.y); o.z = f2bf(v.z); o.w = f2bf(v.w);
    *(ushort4*)(Xb + (size_t)i * 4) = o;
  }
}

// ---------------- W -> packed bf16: Bp[((k>>3)*512 + col)*8 + (k&7)] ----------------
__global__ __launch_bounds__(256) void conv_w(const float* __restrict__ W,
                                              unsigned short* __restrict__ Bp) {
  int idx = blockIdx.x * blockDim.x + threadIdx.x;
  int k = idx >> 9, col = idx & 511;
  Bp[((size_t)(k >> 3) * 512 + col) * 8 + (k & 7)] = f2bf(W[idx]);
}

// ---------------- GEMM: xw_fp8 slice-major = feat_bf @ W (bf16 MFMA, gload_lds staging) ----------------
#define GBM 128
#define GBN 128
#define GBK 32

__global__ __launch_bounds__(256) void gemm_bf16(const unsigned short* __restrict__ A,
                                                 const unsigned short* __restrict__ Bp,
                                                 unsigned char* __restrict__ C8,
                                                 int M, int Mpad) {
  __shared__ __align__(16) unsigned char smem[16384];   // staging, then epilogue tile
  bf16x8* Abuf = (bf16x8*)smem;
  bf16x8* Bbuf = (bf16x8*)(smem + 8192);
  const int tid = threadIdx.x;
  const int lane = tid & 63;
  const int wv = tid >> 6;
  const int wr = wv >> 1, wc = wv & 1;
  const int bm0 = blockIdx.y * GBM;
  const int bn0 = blockIdx.x * GBN;

  f32x4 acc[4][4];
#pragma unroll
  for (int m = 0; m < 4; ++m)
#pragma unroll
    for (int n = 0; n < 4; ++n)
      acc[m][n] = (f32x4){0.f, 0.f, 0.f, 0.f};

  for (int k0 = 0; k0 < NF; k0 += GBK) {
    // async staging: wave-uniform LDS base + lane*16, per-lane global src
#pragma unroll
    for (int c = 0; c < 2; ++c) {
      int slot0 = c * 256 + wv * 64;      // wave-uniform
      int slot = slot0 + lane;
      int kc = slot >> 7;
      int rc = slot & 127;
      int gr = bm0 + rc; if (gr > M - 1) gr = M - 1;
      const unsigned short* gA = A + (size_t)gr * NF + k0 + kc * 8;
      __builtin_amdgcn_global_load_lds((gbl_v*)gA, (lds_v*)(Abuf + slot0), 16, 0, 0);
      int kcg = (k0 >> 3) + kc;
      const unsigned short* gB = Bp + ((size_t)kcg * NH + bn0 + rc) * 8;
      __builtin_amdgcn_global_load_lds((gbl_v*)gB, (lds_v*)(Bbuf + slot0), 16, 0, 0);
    }
    __syncthreads();
    bf16x8 af[4], bfr[4];
#pragma unroll
    for (int m = 0; m < 4; ++m)
      af[m] = Abuf[(lane >> 4) * 128 + wr * 64 + m * 16 + (lane & 15)];
#pragma unroll
    for (int n = 0; n < 4; ++n)
      bfr[n] = Bbuf[(lane >> 4) * 128 + wc * 64 + n * 16 + (lane & 15)];
#pragma unroll
    for (int m = 0; m < 4; ++m)
#pragma unroll
      for (int n = 0; n < 4; ++n)
        acc[m][n] = __builtin_amdgcn_mfma_f32_16x16x32_bf16(af[m], bfr[n], acc[m][n], 0, 0, 0);
    __syncthreads();
  }
  // epilogue: fp8 bytes -> LDS 128x128 tile -> coalesced 16B slice-major stores
#pragma unroll
  for (int m = 0; m < 4; ++m) {
    int rbase = wr * 64 + m * 16 + (lane >> 4) * 4;
#pragma unroll
    for (int n = 0; n < 4; ++n) {
      int col = wc * 64 + n * 16 + (lane & 15);
#pragma unroll
      for (int r = 0; r < 4; ++r) {
        int pk = __builtin_amdgcn_cvt_pk_fp8_f32(acc[m][n][r], 0.f, 0, false);
        smem[(rbase + r) * 128 + col] = (unsigned char)(pk & 0xFF);
      }
    }
  }
  __syncthreads();
  const int sb = bn0 >> 6;    // first slice of this tile (tile spans 2 slices)
#pragma unroll
  for (int c = 0; c < 4; ++c) {
    int id = c * 256 + tid;   // 0..1023 : 128 rows x 8 16B-chunks
    int row = id >> 3;
    int k = id & 7;
    int s = k >> 2;
    int cb = (k & 3) * 16;
    uint4 v = *(const uint4*)(smem + row * 128 + s * 64 + cb);
    *(uint4*)(C8 + ((size_t)(sb + s) * Mpad + bm0 + row) * 64 + cb) = v;
  }
}

// ---------------- edge histogram + degrees (2 edges/thread, vectorized) ----------------
__global__ void hist_kernel(const int* __restrict__ src, const int* __restrict__ dst,
                            const float* __restrict__ gv, int* __restrict__ counts,
                            float* __restrict__ deg, int E) {
  int e = (blockIdx.x * blockDim.x + threadIdx.x) * 2;
  if (e + 1 < E) {
    int2 s2 = *(const int2*)(src + e);
    int2 d2 = *(const int2*)(dst + e);
    float2 g2 = *(const float2*)(gv + e);
    atomicAdd(&counts[s2.x], 1);
    atomicAdd(&counts[s2.y], 1);
    atomicAdd(&deg[d2.x], g2.x);
    atomicAdd(&deg[d2.y], g2.y);
  } else if (e < E) {
    atomicAdd(&counts[src[e]], 1);
    atomicAdd(&deg[dst[e]], gv[e]);
  }
}

// ---------------- parallel 3-phase exclusive scan ----------------
__global__ __launch_bounds__(256) void scanA(const int* __restrict__ counts,
                                             int* __restrict__ bsum, int n) {
  __shared__ int ws[4];
  int i0 = blockIdx.x * 1024 + threadIdx.x * 4;
  int s = 0;
  if (i0 + 3 < n) {
    int4 v = *(const int4*)(counts + i0);
    s = v.x + v.y + v.z + v.w;
  } else {
#pragma unroll
    for (int j = 0; j < 4; ++j) if (i0 + j < n) s += counts[i0 + j];
  }
#pragma unroll
  for (int off = 32; off >= 1; off >>= 1) s += __shfl_down(s, off, 64);
  int wv = threadIdx.x >> 6, ln = threadIdx.x & 63;
  if (ln == 0) ws[wv] = s;
  __syncthreads();
  if (threadIdx.x == 0) bsum[blockIdx.x] = ws[0] + ws[1] + ws[2] + ws[3];
}

__global__ __launch_bounds__(64) void scanB(const int* __restrict__ bsum,
                                            int* __restrict__ bbase,
                                            int* __restrict__ offs, int nb, int n) {
  int ln = threadIdx.x;
  int v = ln < nb ? bsum[ln] : 0;
  int x = v;
#pragma unroll
  for (int d = 1; d < 64; d <<= 1) {
    int y = __shfl_up(x, d, 64);
    if (ln >= d) x += y;
  }
  if (ln < nb) bbase[ln] = x - v;
  if (ln == nb - 1) offs[n] = x;
}

__global__ __launch_bounds__(256) void scanC(const int* __restrict__ counts,
                                             const int* __restrict__ bbase,
                                             int* __restrict__ offs,
                                             int* __restrict__ cursor, int n) {
  __shared__ int ws[4];
  int i0 = blockIdx.x * 1024 + threadIdx.x * 4;
  int c0 = 0, c1 = 0, c2 = 0, c3 = 0;
  if (i0 + 3 < n) {
    int4 v = *(const int4*)(counts + i0);
    c0 = v.x; c1 = v.y; c2 = v.z; c3 = v.w;
  } else {
    if (i0 < n)     c0 = counts[i0];
    if (i0 + 1 < n) c1 = counts[i0 + 1];
    if (i0 + 2 < n) c2 = counts[i0 + 2];
    if (i0 + 3 < n) c3 = counts[i0 + 3];
  }
  int s = c0 + c1 + c2 + c3;
  int x = s;
  int wv = threadIdx.x >> 6, ln = threadIdx.x & 63;
#pragma unroll
  for (int d = 1; d < 64; d <<= 1) {
    int y = __shfl_up(x, d, 64);
    if (ln >= d) x += y;
  }
  if (ln == 63) ws[wv] = x;
  __syncthreads();
  int woff = 0;
  if (wv > 0) woff += ws[0];
  if (wv > 1) woff += ws[1];
  if (wv > 2) woff += ws[2];
  int exc = bbase[blockIdx.x] + woff + x - s;
  if (i0 < n)     { offs[i0]     = exc;                cursor[i0]     = exc; }
  if (i0 + 1 < n) { offs[i0 + 1] = exc + c0;           cursor[i0 + 1] = exc + c0; }
  if (i0 + 2 < n) { offs[i0 + 2] = exc + c0 + c1;      cursor[i0 + 2] = exc + c0 + c1; }
  if (i0 + 3 < n) { offs[i0 + 3] = exc + c0 + c1 + c2; cursor[i0 + 3] = exc + c0 + c1 + c2; }
}

// ---------------- scatter edges into CSR (2 edges/thread) ----------------
__global__ void scatter_kernel(const int* __restrict__ src, const int* __restrict__ dst,
                               const float* __restrict__ gn, int* __restrict__ cursor,
                               int2* __restrict__ epair, int E) {
  int e = (blockIdx.x * blockDim.x + threadIdx.x) * 2;
  if (e + 1 < E) {
    int2 s2 = *(const int2*)(src + e);
    int2 d2 = *(const int2*)(dst + e);
    float2 g2 = *(const float2*)(gn + e);
    int p0 = atomicAdd(&cursor[s2.x], 1);
    int2 v0; v0.x = d2.x; v0.y = __float_as_int(g2.x);
    epair[p0] = v0;
    int p1 = atomicAdd(&cursor[s2.y], 1);
    int2 v1; v1.x = d2.y; v1.y = __float_as_int(g2.y);
    epair[p1] = v1;
  } else if (e < E) {
    int pos = atomicAdd(&cursor[src[e]], 1);
    int2 v; v.x = dst[e]; v.y = __float_as_int(gn[e]);
    epair[pos] = v;
  }
}

// ---------------- sliced SpMM, 8 nodes/block (512 thr, wave per node), 2-deep unroll ----------------
__global__ __launch_bounds__(512) void slice_kernel(const unsigned* __restrict__ xw8,
                                                    const int* __restrict__ offs,
                                                    const int2* __restrict__ epair,
                                                    const float* __restrict__ bias,
                                                    unsigned short* __restrict__ gout,
                                                    int n, int Mpad) {
  __shared__ int sk[512];
  __shared__ float sv[512];
  const int node0 = blockIdx.x * 8;
  const int slice = blockIdx.y;
  const int t = threadIdx.x;
  const int w = t >> 6;         // wave -> node sub-index 0..7
  const int lane = t & 63;
  const int g = lane >> 4;      // edge subgroup 0..3
  const int dw = lane & 15;     // dword within 64 B slice row
  int node = node0 + w;
  int nodec = node < n ? node : n - 1;
  const int nb = offs[nodec], ne = node < n ? offs[nodec + 1] : nb;
  int last = node0 + 8 < n ? node0 + 8 : n;
  const int beg8 = offs[node0], end8 = offs[last];
  const unsigned* base = xw8 + (size_t)slice * Mpad * 16 + dw;

  float a0 = 0.f, a1 = 0.f, a2 = 0.f, a3 = 0.f;

  for (int cbeg = beg8; cbeg < end8; cbeg += 512) {
    int cend = cbeg + 512 < end8 ? cbeg + 512 : end8;
    int cnt = cend - cbeg;
    if (t < cnt) { int2 p = epair[cbeg + t]; sk[t] = p.x; sv[t] = __int_as_float(p.y); }
    __syncthreads();
    int lo = nb > cbeg ? nb : cbeg;
    int hi = ne < cend ? ne : cend;
    int e = lo + g;
    // 2-deep: two independent row-loads in flight per lane
    for (; e + 4 < hi; e += 8) {
      int i0 = e - cbeg, i1 = e + 4 - cbeg;
      int dn0 = sk[i0], dn1 = sk[i1];
      float g0 = sv[i0], g1 = sv[i1];
      unsigned v0 = base[(size_t)dn0 * 16];
      unsigned v1 = base[(size_t)dn1 * 16];
      f32x2 l0 = __builtin_amdgcn_cvt_pk_f32_fp8(v0, false);
      f32x2 h0 = __builtin_amdgcn_cvt_pk_f32_fp8(v0, true);
      f32x2 l1 = __builtin_amdgcn_cvt_pk_f32_fp8(v1, false);
      f32x2 h1 = __builtin_amdgcn_cvt_pk_f32_fp8(v1, true);
      a0 = fmaf(g0, l0[0], a0); a1 = fmaf(g0, l0[1], a1);
      a2 = fmaf(g0, h0[0], a2); a3 = fmaf(g0, h0[1], a3);
      a0 = fmaf(g1, l1[0], a0); a1 = fmaf(g1, l1[1], a1);
      a2 = fmaf(g1, h1[0], a2); a3 = fmaf(g1, h1[1], a3);
    }
    if (e < hi) {
      int idx = e - cbeg;
      int dn = sk[idx];
      float gval = sv[idx];
      unsigned v = base[(size_t)dn * 16];
      f32x2 l2 = __builtin_amdgcn_cvt_pk_f32_fp8(v, false);
      f32x2 h2 = __builtin_amdgcn_cvt_pk_f32_fp8(v, true);
      a0 = fmaf(gval, l2[0], a0); a1 = fmaf(gval, l2[1], a1);
      a2 = fmaf(gval, h2[0], a2); a3 = fmaf(gval, h2[1], a3);
    }
    __syncthreads();
  }

  // reduce across the 4 edge-subgroups (lane>>4) inside the wave
  a0 += __shfl_xor(a0, 16, 64); a1 += __shfl_xor(a1, 16, 64);
  a2 += __shfl_xor(a2, 16, 64); a3 += __shfl_xor(a3, 16, 64);
  a0 += __shfl_xor(a0, 32, 64); a1 += __shfl_xor(a1, 32, 64);
  a2 += __shfl_xor(a2, 32, 64); a3 += __shfl_xor(a3, 32, 64);

  if (g == 0 && node < n) {     // lanes 0..15: dims slice*64 + dw*4 + {0..3}
    int dimb = slice * 64 + dw * 4;
    float v0 = selu_f(a0 + bias[dimb + 0]);
    float v1 = selu_f(a1 + bias[dimb + 1]);
    float v2 = selu_f(a2 + bias[dimb + 2]);
    float v3 = selu_f(a3 + bias[dimb + 3]);
    ushort4 o;
    o.x = f2bf(v0); o.y = f2bf(v1); o.z = f2bf(v2); o.w = f2bf(v3);
    *(ushort4*)(gout + (size_t)node * NH + dimb) = o;
  }
}

// ---------------- projection (512x16) + softmax, one wave per node ----------------
__global__ __launch_bounds__(256) void proj_softmax(const unsigned short* __restrict__ gout,
                                                    const float* __restrict__ Wt,
                                                    const float* __restrict__ bt,
                                                    float* __restrict__ assign, int n) {
  int node = blockIdx.x * 4 + (threadIdx.x >> 6);
  if (node >= n) return;
  int lane = threadIdx.x & 63;
  const unsigned short* row = gout + (size_t)node * NH + lane * 8;
  ushort4 u0 = *(const ushort4*)(row);
  ushort4 u1 = *(const ushort4*)(row + 4);
  float v[8];
  v[0] = __uint_as_float((unsigned)u0.x << 16);
  v[1] = __uint_as_float((unsigned)u0.y << 16);
  v[2] = __uint_as_float((unsigned)u0.z << 16);
  v[3] = __uint_as_float((unsigned)u0.w << 16);
  v[4] = __uint_as_float((unsigned)u1.x << 16);
  v[5] = __uint_as_float((unsigned)u1.y << 16);
  v[6] = __uint_as_float((unsigned)u1.z << 16);
  v[7] = __uint_as_float((unsigned)u1.w << 16);
  float p[NK];
#pragma unroll
  for (int k = 0; k < NK; ++k) p[k] = 0.f;
#pragma unroll
  for (int j = 0; j < 8; ++j) {
    const float* wr = Wt + (size_t)(lane * 8 + j) * NK;
#pragma unroll
    for (int k = 0; k < NK; ++k) p[k] = fmaf(v[j], wr[k], p[k]);
  }
#pragma unroll
  for (int off = 32; off >= 1; off >>= 1)
#pragma unroll
    for (int k = 0; k < NK; ++k) p[k] += __shfl_down(p[k], off, 64);
  if (lane == 0) {
    float l[NK], m = -1e30f;
#pragma unroll
    for (int k = 0; k < NK; ++k) { l[k] = p[k] + bt[k]; m = fmaxf(m, l[k]); }
    float s = 0.f;
#pragma unroll
    for (int k = 0; k < NK; ++k) { l[k] = expf(l[k] - m); s += l[k]; }
    float inv = 1.f / s;
    float4* arow = (float4*)(assign + (size_t)node * NK);
#pragma unroll
    for (int qq = 0; qq < 4; ++qq)
      arow[qq] = make_float4(l[qq * 4] * inv, l[qq * 4 + 1] * inv,
                             l[qq * 4 + 2] * inv, l[qq * 4 + 3] * inv);
  }
}

// ---------------- cs/nl block partials (NO atomics) ----------------
__global__ __launch_bounds__(256) void reduce_cs_nl(const float* __restrict__ assign,
                                                    const float* __restrict__ deg,
                                                    float* __restrict__ P1, int n) {
  __shared__ float lds[4][32];
  float cs[NK] = {}, nl[NK] = {};
  for (int i = blockIdx.x * blockDim.x + threadIdx.x; i < n; i += gridDim.x * blockDim.x) {
    float d = deg[i];
    const float4* ap = (const float4*)(assign + (size_t)i * NK);
#pragma unroll
    for (int q = 0; q < 4; ++q) {
      float4 a = ap[q];
      cs[q * 4 + 0] += a.x; cs[q * 4 + 1] += a.y;
      cs[q * 4 + 2] += a.z; cs[q * 4 + 3] += a.w;
      nl[q * 4 + 0] = fmaf(a.x, d, nl[q * 4 + 0]);
      nl[q * 4 + 1] = fmaf(a.y, d, nl[q * 4 + 1]);
      nl[q * 4 + 2] = fmaf(a.z, d, nl[q * 4 + 2]);
      nl[q * 4 + 3] = fmaf(a.w, d, nl[q * 4 + 3]);
    }
  }
#pragma unroll
  for (int off = 32; off >= 1; off >>= 1) {
#pragma unroll
    for (int k = 0; k < NK; ++k) {
      cs[k] += __shfl_down(cs[k], off, 64);
      nl[k] += __shfl_down(nl[k], off, 64);
    }
  }
  int wave = threadIdx.x >> 6, lane = threadIdx.x & 63;
  if (lane == 0) {
#pragma unroll
    for (int k = 0; k < NK; ++k) { lds[wave][k] = cs[k]; lds[wave][NK + k] = nl[k]; }
  }
  __syncthreads();
  if (threadIdx.x < 32)
    P1[(size_t)blockIdx.x * 32 + threadIdx.x] =
        lds[0][threadIdx.x] + lds[1][threadIdx.x] + lds[2][threadIdx.x] + lds[3][threadIdx.x];
}

// ---------------- trace block partials (2 edges/thread, NO atomics) ----------------
__global__ __launch_bounds__(256) void trace_kernel(const int* __restrict__ src,
                                                    const int* __restrict__ dst,
                                                    const float* __restrict__ gv,
                                                    const float* __restrict__ assign,
                                                    float* __restrict__ T2, int E) {
  __shared__ float lds[4];
  float t = 0.f;
  int step = gridDim.x * blockDim.x * 2;
  for (int e = (blockIdx.x * blockDim.x + threadIdx.x) * 2; e < E; e += step) {
    if (e + 1 < E) {
      int2 s2 = *(const int2*)(src + e);
      int2 d2 = *(const int2*)(dst + e);
      float2 g2 = *(const float2*)(gv + e);
      const float4* as0 = (const float4*)(assign + (size_t)s2.x * NK);
      const float4* ad0 = (const float4*)(assign + (size_t)d2.x * NK);
      const float4* as1 = (const float4*)(assign + (size_t)s2.y * NK);
      const float4* ad1 = (const float4*)(assign + (size_t)d2.y * NK);
      float dot0 = 0.f, dot1 = 0.f;
#pragma unroll
      for (int q = 0; q < 4; ++q) {
        float4 x0 = as0[q], y0 = ad0[q];
        float4 x1 = as1[q], y1 = ad1[q];
        dot0 += x0.x * y0.x + x0.y * y0.y + x0.z * y0.z + x0.w * y0.w;
        dot1 += x1.x * y1.x + x1.y * y1.y + x1.z * y1.z + x1.w * y1.w;
      }
      t = fmaf(g2.x, dot0, t);
      t = fmaf(g2.y, dot1, t);
    } else {
      int s = src[e], d = dst[e];
      const float4* as = (const float4*)(assign + (size_t)s * NK);
      const float4* ad = (const float4*)(assign + (size_t)d * NK);
      float dot = 0.f;
#pragma unroll
      for (int q = 0; q < 4; ++q) {
        float4 x = as[q], y = ad[q];
        dot += x.x * y.x + x.y * y.y + x.z * y.z + x.w * y.w;
      }
      t = fmaf(gv[e], dot, t);
    }
  }
#pragma unroll
  for (int off = 32; off >= 1; off >>= 1) t += __shfl_down(t, off, 64);
  int wave = threadIdx.x >> 6, lane = threadIdx.x & 63;
  if (lane == 0) lds[wave] = t;
  __syncthreads();
  if (threadIdx.x == 0) T2[blockIdx.x] = lds[0] + lds[1] + lds[2] + lds[3];
}

// ---------------- final: sum partials -> scalar ----------------
__global__ __launch_bounds__(256) void final_kernel(const float* __restrict__ P1,
                                                    const float* __restrict__ T2,
                                                    float* __restrict__ out,
                                                    int np1, int np2, int E, int n) {
  __shared__ float arr[256];
  __shared__ float csnl[32];
  const int t = threadIdx.x;
  float s = 0.f;
  for (int p = (t >> 5); p < np1; p += 8) s += P1[(size_t)p * 32 + (t & 31)];
  arr[t] = s;
  __syncthreads();
  if (t < 32) {
    float v = 0.f;
#pragma unroll
    for (int j = 0; j < 8; ++j) v += arr[t + j * 32];
    csnl[t] = v;
  }
  __syncthreads();
  float tv = 0.f;
  for (int p = t; p < np2; p += 256) tv += T2[p];
  arr[t] = tv;
  __syncthreads();
  if (t == 0) {
    float tp = 0.f;
    for (int j = 0; j < 256; ++j) tp += arr[j];
    float sc = 0.f, sn = 0.f;
#pragma unroll
    for (int k = 0; k < NK; ++k) {
      sc += csnl[k] * csnl[k];
      sn += csnl[NK + k] * csnl[NK + k];
    }
    float twoE = 2.0f * (float)E;
    float spectral = -(tp - sn / twoE) / twoE;
    float closs = (sqrtf(sc) / (float)n) * 4.0f - 1.0f;
    out[0] = spectral + closs;
  }
}

extern "C" void kernel_launch(void* const* d_in, const int* in_sizes, int n_in,
                              void* d_out, int out_size, void* d_ws, size_t ws_size,
                              hipStream_t stream) {
  const int*   src  = (const int*)d_in[0];
  const int*   dst  = (const int*)d_in[1];
  const float* gv   = (const float*)d_in[2];
  const float* gn   = (const float*)d_in[3];
  const float* feat = (const float*)d_in[4];
  const float* W    = (const float*)d_in[5];
  const float* b    = (const float*)d_in[6];
  const float* Wt   = (const float*)d_in[7];
  const float* bt   = (const float*)d_in[8];
  const int E = in_sizes[0];
  const int N = in_sizes[4] / NF;
  const int Mblocks = (N + GBM - 1) / GBM;
  const int Mpad = Mblocks * GBM;
  const int nsb = (N + 1023) / 1024;   // scan blocks (49 for N=50000, must be <= 64)

  char* ws = (char*)d_ws;
  size_t off = 0;
  auto alloc = [&](size_t bytes) {
    void* p = ws + off;
    off += (bytes + 255) & ~(size_t)255;
    return p;
  };
  unsigned short* feat_bf = (unsigned short*)alloc((size_t)N * NF * sizeof(unsigned short));
  unsigned short* Wp      = (unsigned short*)alloc((size_t)NF * NH * sizeof(unsigned short));
  unsigned char*  xw8     = (unsigned char*)alloc((size_t)Mpad * NH);   // slice-major
  unsigned short* gout    = (unsigned short*)alloc((size_t)N * NH * sizeof(unsigned short));
  int*   counts = (int*)alloc((size_t)N * sizeof(int));
  int*   offs   = (int*)alloc((size_t)(N + 1) * sizeof(int));
  int*   cursor = (int*)alloc((size_t)N * sizeof(int));
  float* deg    = (float*)alloc((size_t)N * sizeof(float));
  int2*  epair  = (int2*)alloc((size_t)E * sizeof(int2));
  float* assign = (float*)alloc((size_t)N * NK * sizeof(float));
  float* P1     = (float*)alloc((size_t)RPART * 32 * sizeof(float));
  float* T2     = (float*)alloc((size_t)TPART * sizeof(float));
  int*   bsum   = (int*)alloc(64 * sizeof(int));
  int*   bbase  = (int*)alloc(64 * sizeof(int));
  (void)ws_size; (void)n_in; (void)out_size;

  hipMemsetAsync(counts, 0, (size_t)N * sizeof(int), stream);
  hipMemsetAsync(deg, 0, (size_t)N * sizeof(float), stream);

  conv_feat<<<2048, 256, 0, stream>>>(feat, feat_bf, N * NF / 4);
  conv_w<<<(NF * NH) / 256, 256, 0, stream>>>(W, Wp);

  dim3 ggrid(NH / GBN, Mblocks);
  gemm_bf16<<<ggrid, 256, 0, stream>>>(feat_bf, Wp, xw8, N, Mpad);

  int e2blocks = ((E + 1) / 2 + 255) / 256;
  hist_kernel<<<e2blocks, 256, 0, stream>>>(src, dst, gv, counts, deg, E);
  scanA<<<nsb, 256, 0, stream>>>(counts, bsum, N);
  scanB<<<1, 64, 0, stream>>>(bsum, bbase, offs, nsb, N);
  scanC<<<nsb, 256, 0, stream>>>(counts, bbase, offs, cursor, N);
  scatter_kernel<<<e2blocks, 256, 0, stream>>>(src, dst, gn, cursor, epair, E);

  int nblk8 = (N + 7) / 8;
  dim3 sgrid(nblk8, NSLICE);
  slice_kernel<<<sgrid, 512, 0, stream>>>((const unsigned*)xw8, offs, epair, b, gout,
                                          N, Mpad);
  int nblk4 = (N + 3) / 4;
  proj_softmax<<<nblk4, 256, 0, stream>>>(gout, Wt, bt, assign, N);

  reduce_cs_nl<<<RPART, 256, 0, stream>>>(assign, deg, P1, N);
  trace_kernel<<<TPART, 256, 0, stream>>>(src, dst, gv, assign, T2, E);
  final_kernel<<<1, 256, 0, stream>>>(P1, T2, (float*)d_out, RPART, TPART, E, N);
}

// Round 15
// 664.509 us; speedup vs baseline: 1.2393x; 1.2393x over previous
//
#include <hip/hip_runtime.h>
#include <math.h>

#define NN 50000
#define NF 512
#define NH 512
#define NK 16

typedef __attribute__((ext_vector_type(8))) short bf16x8;
typedef __attribute__((ext_vector_type(4))) float f32x4;
typedef __attribute__((ext_vector_type(2))) float f32x2;

#define RPART 128   // reduce_cs_nl blocks
#define TPART 2048  // trace blocks

__device__ __forceinline__ unsigned short f2bf(float f) {
  unsigned u = __float_as_uint(f);
  unsigned r = (u + 0x7fffu + ((u >> 16) & 1u)) >> 16;
  return (unsigned short)r;
}

// ---------------- fp32 -> bf16 feature conversion (once) ----------------
__global__ __launch_bounds__(256) void conv_feat(const float* __restrict__ X,
                                                 unsigned short* __restrict__ Xb, int n4) {
  for (int i = blockIdx.x * blockDim.x + threadIdx.x; i < n4; i += gridDim.x * blockDim.x) {
    float4 v = *(const float4*)(X + (size_t)i * 4);
    ushort4 o;
    o.x = f2bf(v.x); o.y = f2bf(v.y); o.z = f2bf(v.z); o.w = f2bf(v.w);
    *(ushort4*)(Xb + (size_t)i * 4) = o;
  }
}

// ---------------- W -> packed bf16: Bp[((k>>3)*512 + col)*8 + (k&7)] ----------------
__global__ __launch_bounds__(256) void conv_w(const float* __restrict__ W,
                                              unsigned short* __restrict__ Bp) {
  int idx = blockIdx.x * blockDim.x + threadIdx.x;
  int k = idx >> 9, col = idx & 511;
  Bp[((size_t)(k >> 3) * 512 + col) * 8 + (k & 7)] = f2bf(W[idx]);
}

// ---------------- GEMM: xw_fp8[Mpad,512] = feat_bf @ W (bf16 MFMA, fp8 out, row-major) ----------------
#define GBM 128
#define GBN 128
#define GBK 32

__global__ __launch_bounds__(256) void gemm_bf16(const unsigned short* __restrict__ A,
                                                 const unsigned short* __restrict__ Bp,
                                                 unsigned char* __restrict__ C8, int M) {
  __shared__ bf16x8 Abuf[512];
  __shared__ bf16x8 Bbuf[512];
  const int tid = threadIdx.x;
  const int lane = tid & 63;
  const int w = tid >> 6;
  const int wr = w >> 1, wc = w & 1;
  const int bm0 = blockIdx.y * GBM;
  const int bn0 = blockIdx.x * GBN;

  f32x4 acc[4][4];
#pragma unroll
  for (int m = 0; m < 4; ++m)
#pragma unroll
    for (int n = 0; n < 4; ++n)
      acc[m][n] = (f32x4){0.f, 0.f, 0.f, 0.f};

  for (int k0 = 0; k0 < NF; k0 += GBK) {
#pragma unroll
    for (int c = 0; c < 2; ++c) {
      int slot = c * 256 + tid;
      int kc = slot >> 7;
      int rc = slot & 127;
      int gr = bm0 + rc; if (gr > M - 1) gr = M - 1;
      Abuf[slot] = *(const bf16x8*)(A + (size_t)gr * NF + k0 + kc * 8);
      int kcg = (k0 >> 3) + kc;
      Bbuf[slot] = *(const bf16x8*)(Bp + ((size_t)kcg * NH + bn0 + rc) * 8);
    }
    __syncthreads();
    bf16x8 af[4], bfr[4];
#pragma unroll
    for (int m = 0; m < 4; ++m)
      af[m] = Abuf[(lane >> 4) * 128 + wr * 64 + m * 16 + (lane & 15)];
#pragma unroll
    for (int n = 0; n < 4; ++n)
      bfr[n] = Bbuf[(lane >> 4) * 128 + wc * 64 + n * 16 + (lane & 15)];
#pragma unroll
    for (int m = 0; m < 4; ++m)
#pragma unroll
      for (int n = 0; n < 4; ++n)
        acc[m][n] = __builtin_amdgcn_mfma_f32_16x16x32_bf16(af[m], bfr[n], acc[m][n], 0, 0, 0);
    __syncthreads();
  }
#pragma unroll
  for (int m = 0; m < 4; ++m) {
    int grow_base = bm0 + wr * 64 + m * 16 + (lane >> 4) * 4;
#pragma unroll
    for (int r = 0; r < 4; ++r) {
      int grow = grow_base + r;
#pragma unroll
      for (int n = 0; n < 4; ++n) {
        int gcol = bn0 + wc * 64 + n * 16 + (lane & 15);
        int pk = __builtin_amdgcn_cvt_pk_fp8_f32(acc[m][n][r], 0.f, 0, false);
        C8[(size_t)grow * NH + gcol] = (unsigned char)(pk & 0xFF);
      }
    }
  }
}

// ---------------- edge histogram + degrees ----------------
__global__ void hist_kernel(const int* __restrict__ src, const int* __restrict__ dst,
                            const float* __restrict__ gv, int* __restrict__ counts,
                            float* __restrict__ deg, int E) {
  int e = blockIdx.x * blockDim.x + threadIdx.x;
  if (e < E) {
    atomicAdd(&counts[src[e]], 1);
    atomicAdd(&deg[dst[e]], gv[e]);
  }
}

// ---------------- parallel 3-phase exclusive scan ----------------
__global__ __launch_bounds__(256) void scanA(const int* __restrict__ counts,
                                             int* __restrict__ bsum, int n) {
  __shared__ int ws[4];
  int i0 = blockIdx.x * 1024 + threadIdx.x * 4;
  int s = 0;
  if (i0 + 3 < n) {
    int4 v = *(const int4*)(counts + i0);
    s = v.x + v.y + v.z + v.w;
  } else {
#pragma unroll
    for (int j = 0; j < 4; ++j) if (i0 + j < n) s += counts[i0 + j];
  }
#pragma unroll
  for (int off = 32; off >= 1; off >>= 1) s += __shfl_down(s, off, 64);
  int wv = threadIdx.x >> 6, ln = threadIdx.x & 63;
  if (ln == 0) ws[wv] = s;
  __syncthreads();
  if (threadIdx.x == 0) bsum[blockIdx.x] = ws[0] + ws[1] + ws[2] + ws[3];
}

__global__ __launch_bounds__(64) void scanB(const int* __restrict__ bsum,
                                            int* __restrict__ bbase,
                                            int* __restrict__ offs, int nb, int n) {
  int ln = threadIdx.x;
  int v = ln < nb ? bsum[ln] : 0;
  int x = v;
#pragma unroll
  for (int d = 1; d < 64; d <<= 1) {
    int y = __shfl_up(x, d, 64);
    if (ln >= d) x += y;
  }
  if (ln < nb) bbase[ln] = x - v;
  if (ln == nb - 1) offs[n] = x;
}

__global__ __launch_bounds__(256) void scanC(const int* __restrict__ counts,
                                             const int* __restrict__ bbase,
                                             int* __restrict__ offs,
                                             int* __restrict__ cursor, int n) {
  __shared__ int ws[4];
  int i0 = blockIdx.x * 1024 + threadIdx.x * 4;
  int c0 = 0, c1 = 0, c2 = 0, c3 = 0;
  if (i0 + 3 < n) {
    int4 v = *(const int4*)(counts + i0);
    c0 = v.x; c1 = v.y; c2 = v.z; c3 = v.w;
  } else {
    if (i0 < n)     c0 = counts[i0];
    if (i0 + 1 < n) c1 = counts[i0 + 1];
    if (i0 + 2 < n) c2 = counts[i0 + 2];
    if (i0 + 3 < n) c3 = counts[i0 + 3];
  }
  int s = c0 + c1 + c2 + c3;
  int x = s;
  int wv = threadIdx.x >> 6, ln = threadIdx.x & 63;
#pragma unroll
  for (int d = 1; d < 64; d <<= 1) {
    int y = __shfl_up(x, d, 64);
    if (ln >= d) x += y;
  }
  if (ln == 63) ws[wv] = x;
  __syncthreads();
  int woff = 0;
  if (wv > 0) woff += ws[0];
  if (wv > 1) woff += ws[1];
  if (wv > 2) woff += ws[2];
  int exc = bbase[blockIdx.x] + woff + x - s;
  if (i0 < n)     { offs[i0]     = exc;                cursor[i0]     = exc; }
  if (i0 + 1 < n) { offs[i0 + 1] = exc + c0;           cursor[i0 + 1] = exc + c0; }
  if (i0 + 2 < n) { offs[i0 + 2] = exc + c0 + c1;      cursor[i0 + 2] = exc + c0 + c1; }
  if (i0 + 3 < n) { offs[i0 + 3] = exc + c0 + c1 + c2; cursor[i0 + 3] = exc + c0 + c1 + c2; }
}

// ---------------- scatter edges into CSR (paired 8B stores) ----------------
__global__ void scatter_kernel(const int* __restrict__ src, const int* __restrict__ dst,
                               const float* __restrict__ gn, int* __restrict__ cursor,
                               int2* __restrict__ epair, int E) {
  int e = blockIdx.x * blockDim.x + threadIdx.x;
  if (e < E) {
    int pos = atomicAdd(&cursor[src[e]], 1);
    int2 v; v.x = dst[e]; v.y = __float_as_int(gn[e]);
    epair[pos] = v;
  }
}

// ---------------- fused per-node: fp8 SpMM + selu + proj + softmax (R6 config) ----------------
__global__ __launch_bounds__(256) void node_kernel(const unsigned* __restrict__ xw8,
                                                   const int* __restrict__ offs,
                                                   const int2* __restrict__ epair,
                                                   const float* __restrict__ bias,
                                                   const float* __restrict__ Wt,
                                                   const float* __restrict__ bt,
                                                   float* __restrict__ assign, int n) {
  __shared__ int sk[256];
  __shared__ float sv[256];
  __shared__ float cmb[128][4];
  __shared__ float red[2][NK];
  int node = blockIdx.x;
  if (node >= n) return;
  const int t = threadIdx.x;
  const int hl = t & 127;
  const int q = t >> 7;
  const int beg = offs[node], end = offs[node + 1];

  float a0 = 0.f, a1 = 0.f, a2 = 0.f, a3 = 0.f;

  for (int cbeg = beg; cbeg < end; cbeg += 256) {
    int d = end - cbeg; if (d > 256) d = 256;
    if (t < d) { int2 p = epair[cbeg + t]; sk[t] = p.x; sv[t] = __int_as_float(p.y); }
    __syncthreads();
#define ACC(V, G)                                                     \
    { f32x2 lo = __builtin_amdgcn_cvt_pk_f32_fp8(V, false);           \
      f32x2 hi = __builtin_amdgcn_cvt_pk_f32_fp8(V, true);            \
      a0 = fmaf(G, lo[0], a0); a1 = fmaf(G, lo[1], a1);               \
      a2 = fmaf(G, hi[0], a2); a3 = fmaf(G, hi[1], a3); }
    int nf = d & ~7;
    for (int b = 0; b < nf; b += 8) {
      int e0 = b + q, e1 = b + 2 + q, e2 = b + 4 + q, e3 = b + 6 + q;
      int i0 = sk[e0], i1 = sk[e1], i2 = sk[e2], i3 = sk[e3];
      unsigned v0 = xw8[(size_t)i0 * 128 + hl];
      unsigned v1 = xw8[(size_t)i1 * 128 + hl];
      unsigned v2 = xw8[(size_t)i2 * 128 + hl];
      unsigned v3 = xw8[(size_t)i3 * 128 + hl];
      float g0 = sv[e0], g1 = sv[e1], g2 = sv[e2], g3 = sv[e3];
      ACC(v0, g0) ACC(v1, g1) ACC(v2, g2) ACC(v3, g3)
    }
    for (int e = nf + q; e < d; e += 2) {
      unsigned v = xw8[(size_t)sk[e] * 128 + hl];
      float g = sv[e];
      ACC(v, g)
    }
#undef ACC
    __syncthreads();
  }

  if (q == 1) { cmb[hl][0] = a0; cmb[hl][1] = a1; cmb[hl][2] = a2; cmb[hl][3] = a3; }
  __syncthreads();
  if (q == 0) {
    a0 += cmb[hl][0]; a1 += cmb[hl][1]; a2 += cmb[hl][2]; a3 += cmb[hl][3];
    float a[4] = {a0, a1, a2, a3};
    const float SC = 1.0507009873554805f, AL = 1.6732632423543772f;
    float p[NK];
#pragma unroll
    for (int k = 0; k < NK; ++k) p[k] = 0.f;
#pragma unroll
    for (int j = 0; j < 4; ++j) {
      int dim = hl * 4 + j;
      float v = a[j] + bias[dim];
      v = (v > 0.f) ? SC * v : SC * AL * (expf(v) - 1.f);
      const float* wrow = Wt + (size_t)dim * NK;
#pragma unroll
      for (int k = 0; k < NK; ++k) p[k] = fmaf(v, wrow[k], p[k]);
    }
#pragma unroll
    for (int off = 32; off >= 1; off >>= 1)
#pragma unroll
      for (int k = 0; k < NK; ++k) p[k] += __shfl_down(p[k], off, 64);
    int wave = t >> 6, lane = t & 63;
    if (lane == 0) {
#pragma unroll
      for (int k = 0; k < NK; ++k) red[wave][k] = p[k];
    }
  }
  __syncthreads();
  if (t < NK) {
    float l = red[0][t] + red[1][t] + bt[t];
    float m = l;
#pragma unroll
    for (int off = 8; off >= 1; off >>= 1) m = fmaxf(m, __shfl_xor(m, off, 16));
    float ex = expf(l - m);
    float s = ex;
#pragma unroll
    for (int off = 8; off >= 1; off >>= 1) s += __shfl_xor(s, off, 16);
    assign[(size_t)node * NK + t] = ex / s;
  }
}

// ---------------- cs/nl block partials (NO atomics) ----------------
__global__ __launch_bounds__(256) void reduce_cs_nl(const float* __restrict__ assign,
                                                    const float* __restrict__ deg,
                                                    float* __restrict__ P1, int n) {
  __shared__ float lds[4][32];
  float cs[NK] = {}, nl[NK] = {};
  for (int i = blockIdx.x * blockDim.x + threadIdx.x; i < n; i += gridDim.x * blockDim.x) {
    float d = deg[i];
    const float4* ap = (const float4*)(assign + (size_t)i * NK);
#pragma unroll
    for (int q = 0; q < 4; ++q) {
      float4 a = ap[q];
      cs[q * 4 + 0] += a.x; cs[q * 4 + 1] += a.y;
      cs[q * 4 + 2] += a.z; cs[q * 4 + 3] += a.w;
      nl[q * 4 + 0] = fmaf(a.x, d, nl[q * 4 + 0]);
      nl[q * 4 + 1] = fmaf(a.y, d, nl[q * 4 + 1]);
      nl[q * 4 + 2] = fmaf(a.z, d, nl[q * 4 + 2]);
      nl[q * 4 + 3] = fmaf(a.w, d, nl[q * 4 + 3]);
    }
  }
#pragma unroll
  for (int off = 32; off >= 1; off >>= 1) {
#pragma unroll
    for (int k = 0; k < NK; ++k) {
      cs[k] += __shfl_down(cs[k], off, 64);
      nl[k] += __shfl_down(nl[k], off, 64);
    }
  }
  int wave = threadIdx.x >> 6, lane = threadIdx.x & 63;
  if (lane == 0) {
#pragma unroll
    for (int k = 0; k < NK; ++k) { lds[wave][k] = cs[k]; lds[wave][NK + k] = nl[k]; }
  }
  __syncthreads();
  if (threadIdx.x < 32)
    P1[(size_t)blockIdx.x * 32 + threadIdx.x] =
        lds[0][threadIdx.x] + lds[1][threadIdx.x] + lds[2][threadIdx.x] + lds[3][threadIdx.x];
}

// ---------------- trace block partials (NO atomics) ----------------
__global__ __launch_bounds__(256) void trace_kernel(const int* __restrict__ src,
                                                    const int* __restrict__ dst,
                                                    const float* __restrict__ gv,
                                                    const float* __restrict__ assign,
                                                    float* __restrict__ T2, int E) {
  __shared__ float lds[4];
  float t = 0.f;
  for (int e = blockIdx.x * blockDim.x + threadIdx.x; e < E; e += gridDim.x * blockDim.x) {
    int s = src[e], d = dst[e];
    const float4* as = (const float4*)(assign + (size_t)s * NK);
    const float4* ad = (const float4*)(assign + (size_t)d * NK);
    float dot = 0.f;
#pragma unroll
    for (int q = 0; q < 4; ++q) {
      float4 x = as[q], y = ad[q];
      dot += x.x * y.x + x.y * y.y + x.z * y.z + x.w * y.w;
    }
    t = fmaf(gv[e], dot, t);
  }
#pragma unroll
  for (int off = 32; off >= 1; off >>= 1) t += __shfl_down(t, off, 64);
  int wave = threadIdx.x >> 6, lane = threadIdx.x & 63;
  if (lane == 0) lds[wave] = t;
  __syncthreads();
  if (threadIdx.x == 0) T2[blockIdx.x] = lds[0] + lds[1] + lds[2] + lds[3];
}

// ---------------- final: sum partials -> scalar ----------------
__global__ __launch_bounds__(256) void final_kernel(const float* __restrict__ P1,
                                                    const float* __restrict__ T2,
                                                    float* __restrict__ out,
                                                    int np1, int np2, int E, int n) {
  __shared__ float arr[256];
  __shared__ float csnl[32];
  const int t = threadIdx.x;
  float s = 0.f;
  for (int p = (t >> 5); p < np1; p += 8) s += P1[(size_t)p * 32 + (t & 31)];
  arr[t] = s;
  __syncthreads();
  if (t < 32) {
    float v = 0.f;
#pragma unroll
    for (int j = 0; j < 8; ++j) v += arr[t + j * 32];
    csnl[t] = v;
  }
  __syncthreads();
  float tv = 0.f;
  for (int p = t; p < np2; p += 256) tv += T2[p];
  arr[t] = tv;
  __syncthreads();
  if (t == 0) {
    float tp = 0.f;
    for (int j = 0; j < 256; ++j) tp += arr[j];
    float sc = 0.f, sn = 0.f;
#pragma unroll
    for (int k = 0; k < NK; ++k) {
      sc += csnl[k] * csnl[k];
      sn += csnl[NK + k] * csnl[NK + k];
    }
    float twoE = 2.0f * (float)E;
    float spectral = -(tp - sn / twoE) / twoE;
    float closs = (sqrtf(sc) / (float)n) * 4.0f - 1.0f;
    out[0] = spectral + closs;
  }
}

extern "C" void kernel_launch(void* const* d_in, const int* in_sizes, int n_in,
                              void* d_out, int out_size, void* d_ws, size_t ws_size,
                              hipStream_t stream) {
  const int*   src  = (const int*)d_in[0];
  const int*   dst  = (const int*)d_in[1];
  const float* gv   = (const float*)d_in[2];
  const float* gn   = (const float*)d_in[3];
  const float* feat = (const float*)d_in[4];
  const float* W    = (const float*)d_in[5];
  const float* b    = (const float*)d_in[6];
  const float* Wt   = (const float*)d_in[7];
  const float* bt   = (const float*)d_in[8];
  const int E = in_sizes[0];
  const int N = in_sizes[4] / NF;
  const int Mblocks = (N + GBM - 1) / GBM;
  const int Mpad = Mblocks * GBM;
  const int nsb = (N + 1023) / 1024;   // scan blocks (49 for N=50000, <= 64)

  char* ws = (char*)d_ws;
  size_t off = 0;
  auto alloc = [&](size_t bytes) {
    void* p = ws + off;
    off += (bytes + 255) & ~(size_t)255;
    return p;
  };
  unsigned short* feat_bf = (unsigned short*)alloc((size_t)N * NF * sizeof(unsigned short));
  unsigned short* Wp      = (unsigned short*)alloc((size_t)NF * NH * sizeof(unsigned short));
  unsigned char*  xw8     = (unsigned char*)alloc((size_t)Mpad * NH);
  int*   counts = (int*)alloc((size_t)N * sizeof(int));
  int*   offs   = (int*)alloc((size_t)(N + 1) * sizeof(int));
  int*   cursor = (int*)alloc((size_t)N * sizeof(int));
  float* deg    = (float*)alloc((size_t)N * sizeof(float));
  int2*  epair  = (int2*)alloc((size_t)E * sizeof(int2));
  float* assign = (float*)alloc((size_t)N * NK * sizeof(float));
  float* P1     = (float*)alloc((size_t)RPART * 32 * sizeof(float));
  float* T2     = (float*)alloc((size_t)TPART * sizeof(float));
  int*   bsum   = (int*)alloc(64 * sizeof(int));
  int*   bbase  = (int*)alloc(64 * sizeof(int));
  (void)ws_size; (void)n_in; (void)out_size;

  hipMemsetAsync(counts, 0, (size_t)N * sizeof(int), stream);
  hipMemsetAsync(deg, 0, (size_t)N * sizeof(float), stream);

  conv_feat<<<2048, 256, 0, stream>>>(feat, feat_bf, N * NF / 4);
  conv_w<<<(NF * NH) / 256, 256, 0, stream>>>(W, Wp);

  dim3 ggrid(NH / GBN, Mblocks);
  gemm_bf16<<<ggrid, 256, 0, stream>>>(feat_bf, Wp, xw8, N);

  int eblocks = (E + 255) / 256;
  hist_kernel<<<eblocks, 256, 0, stream>>>(src, dst, gv, counts, deg, E);
  scanA<<<nsb, 256, 0, stream>>>(counts, bsum, N);
  scanB<<<1, 64, 0, stream>>>(bsum, bbase, offs, nsb, N);
  scanC<<<nsb, 256, 0, stream>>>(counts, bbase, offs, cursor, N);
  scatter_kernel<<<eblocks, 256, 0, stream>>>(src, dst, gn, cursor, epair, E);

  node_kernel<<<N, 256, 0, stream>>>((const unsigned*)xw8, offs, epair, b, Wt, bt, assign, N);

  reduce_cs_nl<<<RPART, 256, 0, stream>>>(assign, deg, P1, N);
  trace_kernel<<<TPART, 256, 0, stream>>>(src, dst, gv, assign, T2, E);
  final_kernel<<<1, 256, 0, stream>>>(P1, T2, (float*)d_out, RPART, TPART, E, N);
}